// Round 1
// baseline (105.079 us; speedup 1.0000x reference)
//
#include <hip/hip_runtime.h>
#include <math.h>

#define DET 512
#define NA  180
#define OUT 362   // floor(sqrt(512^2/2))
#define RAD 181   // OUT/2

#define NSPLIT 6        // angle partitions per (b, tile)
#define APB    30       // angles per block (NA / NSPLIT)
#define CHUNK  6        // angle lines staged per barrier
#define LSTRIDE 516     // line stride in floats (516*4 bytes, 16B-aligned lines)

// ---------------------------------------------------------------------------
// Compile-time tables (constant memory -> scalar loads, uniform indices).
// ---------------------------------------------------------------------------
constexpr double PI_D = 3.14159265358979323846;

constexpr double tsin(double x) {  // |x| <= pi/4
    double x2 = x * x;
    return x * (1.0 + x2 * (-1.0/6 + x2 * (1.0/120 + x2 * (-1.0/5040 +
               x2 * (1.0/362880 + x2 * (-1.0/39916800))))));
}
constexpr double tcos(double x) {  // |x| <= pi/4
    double x2 = x * x;
    return 1.0 + x2 * (-0.5 + x2 * (1.0/24 + x2 * (-1.0/720 +
               x2 * (1.0/40320 + x2 * (-1.0/3628800)))));
}

struct Trig { float c[NA]; float s[NA]; };
constexpr Trig make_trig() {
    Trig t{};
    constexpr double r = PI_D / 180.0;
    for (int k = 0; k < NA; ++k) {
        double c, s;
        if (k <= 45)       { c =  tcos(k * r);          s =  tsin(k * r); }
        else if (k <= 90)  { c =  tsin((90 - k) * r);   s =  tcos((90 - k) * r); }
        else if (k <= 135) { c = -tsin((k - 90) * r);   s =  tcos((k - 90) * r); }
        else               { c = -tcos((180 - k) * r);  s =  tsin((180 - k) * r); }
        t.c[k] = (float)c; t.s[k] = (float)s;
    }
    return t;
}
__device__ constexpr Trig TRIG = make_trig();

struct WTbl { float w[DET / 2]; };
constexpr WTbl make_wt() {   // w[k] = -2 / (pi * (2k+1))^2
    WTbl t{};
    for (int k = 0; k < DET / 2; ++k) {
        double m = (double)(2 * k + 1);
        t.w[k] = (float)(-2.0 / (PI_D * PI_D * m * m));
    }
    return t;
}
__device__ constexpr WTbl WTC = make_wt();

// ---------------------------------------------------------------------------
// Kernel 1: ramp filter as exact spatial convolution (symmetric-tap form):
//   filtered[d] = 0.5*x[d] + sum_{m odd} w_m * (x[d-m] + x[d+m]),  x zero-padded
// Output layout: ft[b][a][d] (detector contiguous per angle).
// ---------------------------------------------------------------------------
__global__ __launch_bounds__(512) void ramp_filter_kernel(
        const float* __restrict__ x, float* __restrict__ ft) {
    const int a = blockIdx.x;
    const int b = blockIdx.y;
    const int tid = threadIdx.x;   // 0..511

    __shared__ float xs[3 * DET];  // [0,512) zeros | [512,1024) data | [1024,1536) zeros

    xs[tid]        = 0.0f;
    xs[1024 + tid] = 0.0f;
    // x is (B, 1, DET, NA): column read (strided; L2-served, once per element)
    xs[512 + tid]  = x[(b * DET + tid) * NA + a];
    __syncthreads();

    const float* p = xs + 512 + tid;
    float acc = 0.5f * p[0];
    #pragma unroll 4
    for (int k = 0; k < DET / 2; ++k) {
        int m = 2 * k + 1;
        acc = fmaf(WTC.w[k], p[-m] + p[m], acc);
    }
    ft[(b * NA + a) * DET + tid] = acc;
}

// ---------------------------------------------------------------------------
// Kernel 2: backprojection. Grid (12,12,B*NSPLIT); 32x32 pixel tile;
// 4 pixels/thread; CHUNK angle-lines staged per barrier; trig from constant
// memory; no clamps in the lerp (valid pixels have pos in [0.03, 511.97]);
// partials combined with atomicAdd onto memset-zeroed output.
// NSPLIT=6 / CHUNK=6: LDS 12.4KB -> 8 blocks/CU residency (thread-limited),
// 3456 blocks = 13.5/CU of work for latency hiding + load balance.
// ---------------------------------------------------------------------------
__device__ __forceinline__ float interp1(const float* __restrict__ L, float pos) {
    float pf = floorf(pos);
    int   i0 = (int)pf;
    float fr = pos - pf;
    float g0 = L[i0];
    float g1 = L[i0 + 1];          // L[512] is a zero sentinel
    float v  = fmaf(fr, g1 - g0, g0);
    return pos <= (float)(DET - 1) ? v : 0.0f;   // needed: pos can reach 511.97
}

__global__ __launch_bounds__(256, 8) void backproject_kernel(
        const float* __restrict__ ft, float* __restrict__ out) {
    const int bz = blockIdx.z;
    const int b  = bz / NSPLIT;
    const int sp = bz - b * NSPLIT;
    const int r0 = blockIdx.y * 32;
    const int c0 = blockIdx.x * 32;
    const int tid = threadIdx.x;
    const int tx = tid & 15;
    const int ty = tid >> 4;

    __shared__ float line[CHUNK * LSTRIDE];

    // zero sentinels at [c][512] (never overwritten by staging)
    if (tid < CHUNK) line[tid * LSTRIDE + 512] = 0.0f;

    // clamp base coordinate for guard pixels (r/c >= OUT) so their pos stays
    // in-range; their stores are guarded off below.
    const float xpr = (float)(min(r0 + ty, OUT - 1) - RAD);   // row coord
    const float ypr = (float)(min(c0 + tx, OUT - 1) - RAD);   // col coord

    float a00 = 0.0f, a01 = 0.0f, a10 = 0.0f, a11 = 0.0f;

    const float* base = ft + (b * NA + sp * APB) * DET;

    for (int rd = 0; rd < APB / CHUNK; ++rd) {
        __syncthreads();
        const float4* g = (const float4*)(base + rd * CHUNK * DET);
        #pragma unroll
        for (int k = 0; k < (CHUNK * DET / 4) / 256; ++k) {
            int j4 = tid + k * 256;                 // float4 index in chunk
            float4 v = g[j4];
            int c = j4 >> 7;                        // line within chunk
            int d = (j4 & 127) << 2;                // detector offset
            *(float4*)&line[c * LSTRIDE + d] = v;
        }
        __syncthreads();

        const int abase = sp * APB + rd * CHUNK;
        #pragma unroll
        for (int i = 0; i < CHUNK; ++i) {
            const float cv = TRIG.c[abase + i];
            const float sv = TRIG.s[abase + i];
            // pos = ypr*cos - xpr*sin + det/2
            float p00 = fmaf(ypr, cv, fmaf(xpr, -sv, 256.0f));
            float p01 = fmaf(16.0f, cv, p00);       // col+16
            float p10 = fmaf(-16.0f, sv, p00);      // row+16
            float p11 = fmaf(-16.0f, sv, p01);      // row+16, col+16
            const float* L = line + i * LSTRIDE;
            a00 += interp1(L, p00);
            a01 += interp1(L, p01);
            a10 += interp1(L, p10);
            a11 += interp1(L, p11);
        }
    }

    const float scale = (float)(PI_D / (2.0 * NA));
    const int r = r0 + ty;
    const int c = c0 + tx;
    float* ob = out + b * OUT * OUT;
    if (r < OUT) {
        if (c < OUT)      atomicAdd(&ob[r * OUT + c],      a00 * scale);
        if (c + 16 < OUT) atomicAdd(&ob[r * OUT + c + 16], a01 * scale);
    }
    if (r + 16 < OUT) {
        if (c < OUT)      atomicAdd(&ob[(r + 16) * OUT + c],      a10 * scale);
        if (c + 16 < OUT) atomicAdd(&ob[(r + 16) * OUT + c + 16], a11 * scale);
    }
}

extern "C" void kernel_launch(void* const* d_in, const int* in_sizes, int n_in,
                              void* d_out, int out_size, void* d_ws, size_t ws_size,
                              hipStream_t stream) {
    const float* x = (const float*)d_in[0];
    float* ft  = (float*)d_ws;     // B*NA*DET*4 = 1.47 MB scratch
    float* out = (float*)d_out;

    const int B = in_sizes[0] / (DET * NA);   // 4

    hipMemsetAsync(out, 0, (size_t)out_size * sizeof(float), stream);
    ramp_filter_kernel<<<dim3(NA, B), 512, 0, stream>>>(x, ft);
    backproject_kernel<<<dim3((OUT + 31) / 32, (OUT + 31) / 32, B * NSPLIT),
                         256, 0, stream>>>(ft, out);
}